// Round 17
// baseline (97.824 us; speedup 1.0000x reference)
//
#include <hip/hip_runtime.h>
#include <hip/hip_bf16.h>

typedef __bf16 bf16x8 __attribute__((ext_vector_type(8)));
typedef float f32x4 __attribute__((ext_vector_type(4)));

#define LAMBDA_INIT 0.3555090675909693f
#define CEXP 0.18033688011112042f   // 0.125 * log2(e), folded into Q at projection

// ws layout (bytes):
//  q    : [0, 4.19M)       bf16 [16384][128] row-major, PRE-SCALED by CEXP
//  kimg : [4.19M, 8.39M)   bf16 [4][64][2][8 regions][64 slots][8]  (frag image)
//  vimg : [8.39M, 12.58M)  bf16 [4][64][16 regions][64 slots][8]    (frag image)
//  part : [12.58M, +34.1M) recs x 16640B (l[64] f32 + O[64][128] bf16)
//  WT   : after part       bf16 [3][128][1024]
#define K_OFF   ((size_t)16384 * 128)
#define VT_OFF  ((size_t)2 * 16384 * 128)
#define PART_OFF_BYTES ((size_t)12582912)
#define REC_FLOATS 4160  // 64 l + 4096 words of bf16 O

__device__ __forceinline__ unsigned short f2bf(float f) {
    __hip_bfloat16 h = __float2bfloat16(f);
    unsigned short u;
    __builtin_memcpy(&u, &h, 2);
    return u;
}
__device__ __forceinline__ float bf2f(unsigned short u) {
    unsigned int x = ((unsigned int)u) << 16;
    float f;
    __builtin_memcpy(&f, &x, 4);
    return f;
}
__device__ __forceinline__ unsigned int cvt_pk_bf16(float a, float b) {
    unsigned int r;
    asm volatile("v_cvt_pk_bf16_f32 %0, %1, %2" : "=v"(r) : "v"(a), "v"(b));
    return r;
}

// ---------------- W pre-transpose: [1024][128] f32 -> [128][1024] bf16 ----------------
__global__ __launch_bounds__(256) void prep_wt(
    const float* __restrict__ Wq, const float* __restrict__ Wk,
    const float* __restrict__ Wv, unsigned short* __restrict__ WT) {
    const int kt = blockIdx.x, nt = blockIdx.y, mat = blockIdx.z;
    const float* W = (mat == 0) ? Wq : (mat == 1) ? Wk : Wv;
    unsigned short* O = WT + (size_t)mat * 128 * 1024;
    __shared__ float tb[64][65];
    const int r = threadIdx.x >> 2, c4 = (threadIdx.x & 3) * 16;
    for (int j = 0; j < 4; ++j) {
        float4 v = *(const float4*)&W[(size_t)(kt * 64 + r) * 128 + nt * 64 + c4 + j * 4];
        tb[r][c4 + j * 4 + 0] = v.x;
        tb[r][c4 + j * 4 + 1] = v.y;
        tb[r][c4 + j * 4 + 2] = v.z;
        tb[r][c4 + j * 4 + 3] = v.w;
    }
    __syncthreads();
    unsigned short tmp[16];
    for (int j = 0; j < 16; ++j) tmp[j] = f2bf(tb[c4 + j][r]);
    *(uint4*)&O[(size_t)(nt * 64 + r) * 1024 + kt * 64 + c4] = *(uint4*)&tmp[0];
    *(uint4*)&O[(size_t)(nt * 64 + r) * 1024 + kt * 64 + c4 + 8] = *(uint4*)&tmp[8];
}

// ---------------- QKV projection, 64-row tiles, 2-deep reg-prefetched staging ----------
// grid (256, 3): 768 blocks = exactly 3/CU, co-resident, zero makespan skew.
// id = rx + 256*mat: same row-tile across mats on SAME XCD (256%8==0) -> x L2/L3 hits.
// Two named staging sets issued 2 k-steps ahead: each load gets a full k-step
// (+barriers) of flight time (1-deep's ~300cyc window barely covered latency).
__global__ __launch_bounds__(256, 3) void qkv_gemm(
    const float* __restrict__ x, const unsigned short* __restrict__ WT,
    unsigned short* __restrict__ qkv) {
    const int tid = threadIdx.x;
    const int l = tid & 63, w = tid >> 6;
    const int g = l >> 4, i16 = l & 15;
    const int row0 = blockIdx.x * 64;
    const int mat = blockIdx.y;
    const unsigned short* Wt = WT + (size_t)mat * 128 * 1024;

    __shared__ unsigned short xs[64][72];
    __shared__ unsigned short wt[128][72];

    f32x4 acc[8];
    const f32x4 z4 = {0.f, 0.f, 0.f, 0.f};
    for (int nb = 0; nb < 8; ++nb) acc[nb] = z4;

    const int xr = tid >> 4;             // + it*16
    const int xc = (tid & 15) * 4;
    const int wn = tid >> 3;             // + it*32
    const int wk8 = (tid & 7) * 8;
    const float* xp0 = &x[(size_t)(row0 + xr) * 1024 + xc];
    const unsigned short* wp0 = &Wt[(size_t)wn * 1024 + wk8];

    float4 ax0, ax1, ax2, ax3, bx0, bx1, bx2, bx3;
    uint4 aw0, aw1, aw2, aw3, bw0, bw1, bw2, bw3;

#define QI(k0_, X0, X1, X2, X3, W0, W1, W2, W3) do {                        \
        X0 = *(const float4*)&xp0[(k0_)];                                   \
        X1 = *(const float4*)&xp0[16 * 1024 + (k0_)];                       \
        X2 = *(const float4*)&xp0[32 * 1024 + (k0_)];                       \
        X3 = *(const float4*)&xp0[48 * 1024 + (k0_)];                       \
        W0 = *(const uint4*)&wp0[(k0_)];                                    \
        W1 = *(const uint4*)&wp0[32 * 1024 + (k0_)];                        \
        W2 = *(const uint4*)&wp0[64 * 1024 + (k0_)];                        \
        W3 = *(const uint4*)&wp0[96 * 1024 + (k0_)];                        \
    } while (0)

#define QS(X0, X1, X2, X3, W0, W1, W2, W3) do {                             \
        *(ushort4*)&xs[xr +  0][xc] = make_ushort4(f2bf(X0.x), f2bf(X0.y), f2bf(X0.z), f2bf(X0.w)); \
        *(ushort4*)&xs[xr + 16][xc] = make_ushort4(f2bf(X1.x), f2bf(X1.y), f2bf(X1.z), f2bf(X1.w)); \
        *(ushort4*)&xs[xr + 32][xc] = make_ushort4(f2bf(X2.x), f2bf(X2.y), f2bf(X2.z), f2bf(X2.w)); \
        *(ushort4*)&xs[xr + 48][xc] = make_ushort4(f2bf(X3.x), f2bf(X3.y), f2bf(X3.z), f2bf(X3.w)); \
        *(uint4*)&wt[wn +  0][wk8] = W0;                                    \
        *(uint4*)&wt[wn + 32][wk8] = W1;                                    \
        *(uint4*)&wt[wn + 64][wk8] = W2;                                    \
        *(uint4*)&wt[wn + 96][wk8] = W3;                                    \
    } while (0)

#define QMFMA() do {                                                        \
        bf16x8 af0 = *(const bf16x8*)&xs[w * 16 + i16][8 * g];              \
        bf16x8 af1 = *(const bf16x8*)&xs[w * 16 + i16][32 + 8 * g];         \
        _Pragma("unroll")                                                   \
        for (int nb = 0; nb < 8; ++nb) {                                    \
            bf16x8 b0 = *(const bf16x8*)&wt[nb * 16 + i16][8 * g];          \
            bf16x8 b1 = *(const bf16x8*)&wt[nb * 16 + i16][32 + 8 * g];     \
            acc[nb] = __builtin_amdgcn_mfma_f32_16x16x32_bf16(af0, b0, acc[nb], 0, 0, 0); \
            acc[nb] = __builtin_amdgcn_mfma_f32_16x16x32_bf16(af1, b1, acc[nb], 0, 0, 0); \
        }                                                                   \
    } while (0)

    QI(0, ax0, ax1, ax2, ax3, aw0, aw1, aw2, aw3);
    QI(64, bx0, bx1, bx2, bx3, bw0, bw1, bw2, bw3);
    #pragma unroll 1
    for (int k0 = 0; k0 < 1024; k0 += 128) {
        __syncthreads();
        QS(ax0, ax1, ax2, ax3, aw0, aw1, aw2, aw3);
        if (k0 + 128 < 1024) QI(k0 + 128, ax0, ax1, ax2, ax3, aw0, aw1, aw2, aw3);
        __syncthreads();
        QMFMA();
        __syncthreads();
        QS(bx0, bx1, bx2, bx3, bw0, bw1, bw2, bw3);
        if (k0 + 192 < 1024) QI(k0 + 192, bx0, bx1, bx2, bx3, bw0, bw1, bw2, bw3);
        __syncthreads();
        QMFMA();
    }
#undef QI
#undef QS
#undef QMFMA

    // epilogue: bounce through LDS (alias over wt), then frag-image writes
    __syncthreads();
    unsigned short(*ts)[136] = (unsigned short(*)[136]) & wt[0][0];
    const float qscale = (mat == 0) ? CEXP : 1.0f;
    for (int nb = 0; nb < 8; ++nb)
        for (int r = 0; r < 4; ++r)
            ts[w * 16 + g * 4 + r][nb * 16 + i16] = f2bf(acc[nb][r] * qscale);
    __syncthreads();

    const int bq = row0 >> 12;           // batch
    const int s = (row0 >> 6) & 63;      // kv-tile index
    if (mat == 0) {
        unsigned short* outp = qkv + (size_t)row0 * 128;
        #pragma unroll
        for (int it = 0; it < 4; ++it) {
            int tr = it * 16 + (tid >> 4), dv0 = (tid & 15) * 8;
            *(uint4*)&outp[tr * 128 + dv0] = *(const uint4*)&ts[tr][dv0];
        }
    } else if (mat == 1) {
        unsigned short* kimg = qkv + K_OFF + ((size_t)(bq * 64 + s) * 2) * 4096;
        #pragma unroll
        for (int it = 0; it < 4; ++it) {
            int lin = it * 256 + tid;
            int branch_ = (lin >> 9) & 1;
            int region = (lin >> 6) & 7;
            int slot = lin & 63;
            int row = (region >> 1) * 16 + (slot & 15);
            int d = branch_ * 64 + (region & 1) * 32 + (slot >> 4) * 8;
            uint4 vv = *(const uint4*)&ts[row][d];
            *(uint4*)&kimg[(size_t)branch_ * 4096 + (region * 64 + slot) * 8] = vv;
        }
    } else {
        unsigned short* vimg = qkv + VT_OFF + (size_t)(bq * 64 + s) * 8192;
        #pragma unroll
        for (int it = 0; it < 4; ++it) {
            int lin = it * 256 + tid;
            int region = lin >> 6;
            int slot = lin & 63;
            int dv = (region >> 1) * 16 + (slot & 15);
            int kv0 = (region & 1) * 32 + (slot >> 4) * 8;
            unsigned short tmp[8];
            #pragma unroll
            for (int e = 0; e < 8; ++e) tmp[e] = ts[kv0 + e][dv];
            *(uint4*)&vimg[(region * 64 + slot) * 8] = *(uint4*)tmp;
        }
    }
}

// ---------------- Differential causal flash attention, paired rows ----------------
// grid (32, 4, nc*2): z = c*2+branch, nc = 4. Block owns adjacent row PAIR
// (t_e, t_o); COMPLEMENT SWIZZLE bxe = (c&1)?31-bx:bx balances CU totals.
// FUSED QK: each kf read once, 2 MFMA (A,B) -> 8 LDS reads not 16.
// DOUBLE-BUFFERED ksf -> 2 barriers/tile (was 3): store ksf[pb] for tile s
// conflicts with nothing (last read at tile s-2, fenced by B3(s-2..s-1));
// merged barrier also fences psf rewrite vs prev PV reads.
// Q pre-scaled by CEXP; p = exp2(S'). PV: V in registers, dv-split, psf 16KB.
// LDS = 32KB. Empty chunks return without writing; combine skips.
__global__ __launch_bounds__(256, 3) void diff_attn_pair(
    const unsigned short* __restrict__ q, const unsigned short* __restrict__ kimg,
    const unsigned short* __restrict__ vimg,
    float* __restrict__ part, int ncs) {
    const int bx = blockIdx.x, b = blockIdx.y;
    const int c = blockIdx.z >> 1, branch = blockIdx.z & 1;
    const int bxe = (c & 1) ? (31 - bx) : bx;
    const int t_o = 63 - 2 * bxe, t_e = t_o - 1;
    const int n = t_o + 1;
    const int s_lo = (c * n) >> ncs, smax = ((c + 1) * n) >> ncs;

    if (s_lo >= smax) return;

    const int tid = threadIdx.x;
    const int l = tid & 63, w = tid >> 6;
    const int gq = l >> 4, i16 = l & 15;
    const float NEGINF = -__builtin_inff();

    __shared__ unsigned short ksf[2][4096];  // 16 KB double-buffered K frag image
    __shared__ unsigned short psf[8192];     // 16 KB: [2 qset][4 qg][2 cc][64 slot][8]

    float* recA = part + ((((size_t)(b * 64 + t_e) << ncs) + c) * 2 + branch) * REC_FLOATS;
    float* recB = part + ((((size_t)(b * 64 + t_o) << ncs) + c) * 2 + branch) * REC_FLOATS;
    const bool emptyA = (s_lo > t_e);

    const size_t bbase = (size_t)b * 4096;
    const unsigned short* kimg_b = kimg + (size_t)b * 524288;
    const unsigned short* vimg_b = vimg + (size_t)b * 524288;
    const int tid8 = tid * 8;
    const int l8 = l * 8;
    const f32x4 z4 = {0.f, 0.f, 0.f, 0.f};

    bf16x8 qfA[2], qfB[2];
    #pragma unroll
    for (int cc = 0; cc < 2; ++cc) {
        qfA[cc] = *(const bf16x8*)&q[(bbase + t_e * 64 + w * 16 + i16) * 128 + branch * 64 + cc * 32 + 8 * gq];
        qfB[cc] = *(const bf16x8*)&q[(bbase + t_o * 64 + w * 16 + i16) * 128 + branch * 64 + cc * 32 + 8 * gq];
    }

    float lsumA = 0.f, lsumB = 0.f;
    f32x4 acc[2][4][2];
    for (int qs = 0; qs < 2; ++qs)
        for (int qg = 0; qg < 4; ++qg)
            for (int j = 0; j < 2; ++j) acc[qs][qg][j] = z4;

    int pdst[4];
    #pragma unroll
    for (int cb = 0; cb < 4; ++cb)
        pdst[cb] = ((w * 2 + (cb >> 1)) * 64 + ((cb & 1) * 2 + (gq >> 1)) * 16 + i16) * 8 + (gq & 1) * 4;

    uint4 kr0, kr1;
    bf16x8 vb00, vb01, vb10, vb11;

#define K_ISSUE(s_) do {                                                            \
        const unsigned short* kp = &kimg_b[((size_t)(s_) * 2 + branch) * 4096];     \
        kr0 = *(const uint4*)&kp[tid8];                                             \
        kr1 = *(const uint4*)&kp[tid8 + 2048];                                      \
    } while (0)
#define V_ISSUE(s_) do {                                                            \
        const unsigned short* vp = &vimg_b[(size_t)(s_) * 8192 + w * 2048];         \
        vb00 = *(const bf16x8*)&vp[l8];                                             \
        vb01 = *(const bf16x8*)&vp[512 + l8];                                       \
        vb10 = *(const bf16x8*)&vp[1024 + l8];                                      \
        vb11 = *(const bf16x8*)&vp[1536 + l8];                                      \
    } while (0)

    K_ISSUE(s_lo);
    V_ISSUE(s_lo);
    int pb = 0;
    #pragma unroll 1
    for (int s = s_lo; s < smax; ++s) {
        // store ksf[pb]: last read at tile s-2 (same pb), fenced by B3 chain
        *(uint4*)&ksf[pb][tid8] = kr0;
        *(uint4*)&ksf[pb][tid8 + 2048] = kr1;
        if (s + 1 < smax) K_ISSUE(s + 1);
        __syncthreads();   // MERGED: ksf[pb] ready + prev PV done reading psf
        const bool aAct = (s != t_o);

        // ---- fused QK: one kf read feeds both qsets ----
        f32x4 scA[4], scB[4];
        for (int cb = 0; cb < 4; ++cb) { scA[cb] = z4; scB[cb] = z4; }
        __builtin_amdgcn_s_setprio(1);
        #pragma unroll
        for (int cb = 0; cb < 4; ++cb)
            for (int cc = 0; cc < 2; ++cc) {
                bf16x8 kf = *(const bf16x8*)&ksf[pb][((cb * 2 + cc) * 64 + l) * 8];
                scA[cb] = __builtin_amdgcn_mfma_f32_16x16x32_bf16(kf, qfA[cc], scA[cb], 0, 0, 0);
                scB[cb] = __builtin_amdgcn_mfma_f32_16x16x32_bf16(kf, qfB[cc], scB[cb], 0, 0, 0);
            }
        __builtin_amdgcn_s_setprio(0);

        // ---- softmax A ----
        if (aAct) {
            if (s == t_e) {
                int ql = w * 16 + i16;
                for (int cb = 0; cb < 4; ++cb)
                    for (int r = 0; r < 4; ++r)
                        if (cb * 16 + gq * 4 + r > ql) scA[cb][r] = NEGINF;
            }
            #pragma unroll
            for (int cb = 0; cb < 4; ++cb) {
                float p0 = exp2f(scA[cb][0]);
                float p1 = exp2f(scA[cb][1]);
                float p2 = exp2f(scA[cb][2]);
                float p3 = exp2f(scA[cb][3]);
                lsumA += (p0 + p1) + (p2 + p3);
                uint2 pw;
                pw.x = cvt_pk_bf16(p0, p1);
                pw.y = cvt_pk_bf16(p2, p3);
                *(uint2*)&psf[pdst[cb]] = pw;
            }
        }
        // ---- softmax B ----
        {
            if (s == t_o) {
                int ql = w * 16 + i16;
                for (int cb = 0; cb < 4; ++cb)
                    for (int r = 0; r < 4; ++r)
                        if (cb * 16 + gq * 4 + r > ql) scB[cb][r] = NEGINF;
            }
            #pragma unroll
            for (int cb = 0; cb < 4; ++cb) {
                float p0 = exp2f(scB[cb][0]);
                float p1 = exp2f(scB[cb][1]);
                float p2 = exp2f(scB[cb][2]);
                float p3 = exp2f(scB[cb][3]);
                lsumB += (p0 + p1) + (p2 + p3);
                uint2 pw;
                pw.x = cvt_pk_bf16(p0, p1);
                pw.y = cvt_pk_bf16(p2, p3);
                *(uint2*)&psf[4096 + pdst[cb]] = pw;
            }
        }
        __syncthreads();   // psf complete (cross-wave)

        // ---- PV: all q x dv-slice [w*32, w*32+32), V in registers ----
        __builtin_amdgcn_s_setprio(1);
        if (aAct) {
            #pragma unroll
            for (int qg = 0; qg < 4; ++qg) {
                bf16x8 pa0 = *(const bf16x8*)&psf[(qg * 2 + 0) * 512 + l8];
                bf16x8 pa1 = *(const bf16x8*)&psf[(qg * 2 + 1) * 512 + l8];
                acc[0][qg][0] = __builtin_amdgcn_mfma_f32_16x16x32_bf16(pa0, vb00, acc[0][qg][0], 0, 0, 0);
                acc[0][qg][0] = __builtin_amdgcn_mfma_f32_16x16x32_bf16(pa1, vb01, acc[0][qg][0], 0, 0, 0);
                acc[0][qg][1] = __builtin_amdgcn_mfma_f32_16x16x32_bf16(pa0, vb10, acc[0][qg][1], 0, 0, 0);
                acc[0][qg][1] = __builtin_amdgcn_mfma_f32_16x16x32_bf16(pa1, vb11, acc[0][qg][1], 0, 0, 0);
            }
        }
        #pragma unroll
        for (int qg = 0; qg < 4; ++qg) {
            bf16x8 pa0 = *(const bf16x8*)&psf[4096 + (qg * 2 + 0) * 512 + l8];
            bf16x8 pa1 = *(const bf16x8*)&psf[4096 + (qg * 2 + 1) * 512 + l8];
            acc[1][qg][0] = __builtin_amdgcn_mfma_f32_16x16x32_bf16(pa0, vb00, acc[1][qg][0], 0, 0, 0);
            acc[1][qg][0] = __builtin_amdgcn_mfma_f32_16x16x32_bf16(pa1, vb01, acc[1][qg][0], 0, 0, 0);
            acc[1][qg][1] = __builtin_amdgcn_mfma_f32_16x16x32_bf16(pa0, vb10, acc[1][qg][1], 0, 0, 0);
            acc[1][qg][1] = __builtin_amdgcn_mfma_f32_16x16x32_bf16(pa1, vb11, acc[1][qg][1], 0, 0, 0);
        }
        __builtin_amdgcn_s_setprio(0);
        if (s + 1 < smax) V_ISSUE(s + 1);
        pb ^= 1;
    }
#undef K_ISSUE
#undef V_ISSUE

    // flush
    lsumA += __shfl_xor(lsumA, 16);
    lsumA += __shfl_xor(lsumA, 32);
    lsumB += __shfl_xor(lsumB, 16);
    lsumB += __shfl_xor(lsumB, 32);
    if (!emptyA) {
        if (gq == 0) recA[w * 16 + i16] = lsumA;
        unsigned short* OA = (unsigned short*)(recA + 64);
        for (int qg = 0; qg < 4; ++qg)
            for (int j = 0; j < 2; ++j)
                for (int r = 0; r < 4; ++r)
                    OA[(qg * 16 + gq * 4 + r) * 128 + (w * 2 + j) * 16 + i16] = f2bf(acc[0][qg][j][r]);
    }
    {
        if (gq == 0) recB[w * 16 + i16] = lsumB;
        unsigned short* OB = (unsigned short*)(recB + 64);
        for (int qg = 0; qg < 4; ++qg)
            for (int j = 0; j < 2; ++j)
                for (int r = 0; r < 4; ++r)
                    OB[(qg * 16 + gq * 4 + r) * 128 + (w * 2 + j) * 16 + i16] = f2bf(acc[1][qg][j][r]);
    }
}

// ---------------- combine: sum valid chunks per branch, normalize, o1 - lam*o2 ----------
__global__ __launch_bounds__(256) void diff_combine(
    const float* __restrict__ part,
    const float* __restrict__ lq1, const float* __restrict__ lq2,
    const float* __restrict__ lk1, const float* __restrict__ lk2,
    float* __restrict__ out, int ncs) {
    const int t = blockIdx.x, b = blockIdx.y;
    const int tid = threadIdx.x;
    const int nc = 1 << ncs;
    const int n = (t | 1) + 1;
    __shared__ float sl[2][64];
    __shared__ float s_lam;

    const float* recbase = part + (((size_t)(b * 64 + t) << ncs)) * 2 * REC_FLOATS;

    if (tid < 64) {
        float s1 = lq1[tid] * lk1[tid];
        float s2 = lq2[tid] * lk2[tid];
        for (int off = 32; off > 0; off >>= 1) {
            s1 += __shfl_xor(s1, off);
            s2 += __shfl_xor(s2, off);
        }
        if (tid == 0) s_lam = expf(s1) - expf(s2) + LAMBDA_INIT;
    }
    if (tid < 128) {
        int r = tid & 63, br = tid >> 6;
        float acc = 0.f;
        for (int c = 0; c < nc; ++c) {
            int lo = (c * n) >> ncs, hi = ((c + 1) * n) >> ncs;
            if (lo >= hi || lo > t) continue;
            acc += recbase[(c * 2 + br) * REC_FLOATS + r];
        }
        sl[br][r] = acc;
    }
    __syncthreads();
    const float lam = s_lam;

    float* op = out + ((size_t)b * 4096 + (size_t)t * 64) * 128;
    for (int grp = 0; grp < 4; ++grp) {
        int gid = grp * 256 + tid;
        int e = gid * 8;
        int row = e >> 7;
        float o1[8] = {0, 0, 0, 0, 0, 0, 0, 0}, o2[8] = {0, 0, 0, 0, 0, 0, 0, 0};
        for (int c = 0; c < nc; ++c) {
            int lo = (c * n) >> ncs, hi = ((c + 1) * n) >> ncs;
            if (lo >= hi || lo > t) continue;
            const unsigned short* O0 = (const unsigned short*)(recbase + (c * 2 + 0) * REC_FLOATS + 64);
            const unsigned short* O1 = (const unsigned short*)(recbase + (c * 2 + 1) * REC_FLOATS + 64);
            uint4 u0 = *(const uint4*)&O0[e];
            uint4 u1 = *(const uint4*)&O1[e];
            const unsigned short* e0 = (const unsigned short*)&u0;
            const unsigned short* e1 = (const unsigned short*)&u1;
            #pragma unroll
            for (int j = 0; j < 8; ++j) {
                o1[j] += bf2f(e0[j]);
                o2[j] += bf2f(e1[j]);
            }
        }
        float l1inv = 1.0f / sl[0][row], l2inv = 1.0f / sl[1][row];
        float res[8];
        #pragma unroll
        for (int j = 0; j < 8; ++j) res[j] = o1[j] * l1inv - lam * o2[j] * l2inv;
        *(float4*)&op[e] = *(float4*)&res[0];
        *(float4*)&op[e + 4] = *(float4*)&res[4];
    }
}

extern "C" void kernel_launch(void* const* d_in, const int* in_sizes, int n_in,
                              void* d_out, int out_size, void* d_ws, size_t ws_size,
                              hipStream_t stream) {
    const float* x   = (const float*)d_in[0];
    const float* Wq  = (const float*)d_in[1];
    const float* Wk  = (const float*)d_in[2];
    const float* Wv  = (const float*)d_in[3];
    const float* lq1 = (const float*)d_in[4];
    const float* lq2 = (const float*)d_in[5];
    const float* lk1 = (const float*)d_in[6];
    const float* lk2 = (const float*)d_in[7];
    float* out = (float*)d_out;
    unsigned short* qkv = (unsigned short*)d_ws;

    const int ncs = 2;  // 4 kv-chunks
    const size_t part_bytes = (size_t)256 * (1 << ncs) * 2 * REC_FLOATS * 4;
    float* part = (float*)((char*)d_ws + PART_OFF_BYTES);
    unsigned short* WT = (unsigned short*)((char*)d_ws + PART_OFF_BYTES + part_bytes);

    prep_wt<<<dim3(16, 2, 3), 256, 0, stream>>>(Wq, Wk, Wv, WT);
    qkv_gemm<<<dim3(256, 3), 256, 0, stream>>>(x, WT, qkv);

    const unsigned short* qb = qkv;
    const unsigned short* kb = qkv + K_OFF;
    const unsigned short* vtb = qkv + VT_OFF;
    diff_attn_pair<<<dim3(32, 4, 2 << ncs), 256, 0, stream>>>(qb, kb, vtb, part, ncs);
    diff_combine<<<dim3(64, 4), 256, 0, stream>>>(part, lq1, lq2, lk1, lk2, out, ncs);
}

// Round 18
// 92.894 us; speedup vs baseline: 1.0531x; 1.0531x over previous
//
#include <hip/hip_runtime.h>
#include <hip/hip_bf16.h>

typedef __bf16 bf16x8 __attribute__((ext_vector_type(8)));
typedef float f32x4 __attribute__((ext_vector_type(4)));

#define LAMBDA_INIT 0.3555090675909693f
#define CEXP 0.18033688011112042f   // 0.125 * log2(e), folded into Q at projection

// ws layout (bytes):
//  q    : [0, 4.19M)       bf16 [16384][128] row-major, PRE-SCALED by CEXP
//  kimg : [4.19M, 8.39M)   bf16 [4][64][2][8 regions][64 slots][8]  (frag image)
//  vimg : [8.39M, 12.58M)  bf16 [4][64][16 regions][64 slots][8]    (frag image)
//  part : [12.58M, +34.1M) recs x 16640B (l[64] f32 + O[64][128] bf16)
//  WT   : after part       bf16 [3][128][1024] == W'[384][1024]
#define K_OFF   ((size_t)16384 * 128)
#define VT_OFF  ((size_t)2 * 16384 * 128)
#define PART_OFF_BYTES ((size_t)12582912)
#define REC_FLOATS 4160  // 64 l + 4096 words of bf16 O

__device__ __forceinline__ unsigned short f2bf(float f) {
    __hip_bfloat16 h = __float2bfloat16(f);
    unsigned short u;
    __builtin_memcpy(&u, &h, 2);
    return u;
}
__device__ __forceinline__ float bf2f(unsigned short u) {
    unsigned int x = ((unsigned int)u) << 16;
    float f;
    __builtin_memcpy(&f, &x, 4);
    return f;
}
__device__ __forceinline__ unsigned int cvt_pk_bf16(float a, float b) {
    unsigned int r;
    asm volatile("v_cvt_pk_bf16_f32 %0, %1, %2" : "=v"(r) : "v"(a), "v"(b));
    return r;
}

// ---------------- W pre-transpose: [1024][128] f32 -> [128][1024] bf16 ----------------
__global__ __launch_bounds__(256) void prep_wt(
    const float* __restrict__ Wq, const float* __restrict__ Wk,
    const float* __restrict__ Wv, unsigned short* __restrict__ WT) {
    const int kt = blockIdx.x, nt = blockIdx.y, mat = blockIdx.z;
    const float* W = (mat == 0) ? Wq : (mat == 1) ? Wk : Wv;
    unsigned short* O = WT + (size_t)mat * 128 * 1024;
    __shared__ float tb[64][65];
    const int r = threadIdx.x >> 2, c4 = (threadIdx.x & 3) * 16;
    for (int j = 0; j < 4; ++j) {
        float4 v = *(const float4*)&W[(size_t)(kt * 64 + r) * 128 + nt * 64 + c4 + j * 4];
        tb[r][c4 + j * 4 + 0] = v.x;
        tb[r][c4 + j * 4 + 1] = v.y;
        tb[r][c4 + j * 4 + 2] = v.z;
        tb[r][c4 + j * 4 + 3] = v.w;
    }
    __syncthreads();
    unsigned short tmp[16];
    for (int j = 0; j < 16; ++j) tmp[j] = f2bf(tb[c4 + j][r]);
    *(uint4*)&O[(size_t)(nt * 64 + r) * 1024 + kt * 64 + c4] = *(uint4*)&tmp[0];
    *(uint4*)&O[(size_t)(nt * 64 + r) * 1024 + kt * 64 + c4 + 8] = *(uint4*)&tmp[8];
}

// ---------------- Fused QKV: ONE GEMM [16384x1024] x [1024x384] ----------------
// x is read from HBM ONCE (the 3-kernel version read it 3x: ~17-25us of L3/HBM
// re-reads). grid 256 = exactly 1 block/CU (all identical); 512 thr = 8 waves
// (2/SIMD). Wave (rh=w>>2, cp=w&3): rows rh*32+[0,32), cols cp*96+[0,96).
// W' k-slice (384x64, 48KB) staged per k-step (re-reads hit L2: W'=768KB).
// 2-deep named-reg prefetch. Epilogue: 64x392 ts bounce (CEXP on cols<128,
// f32-applied), then q / K-frag-image / V-frag-image writes.
__global__ __launch_bounds__(512) void qkv_fused(
    const float* __restrict__ x, const unsigned short* __restrict__ WT,
    unsigned short* __restrict__ qkv) {
    const int tid = threadIdx.x;
    const int l = tid & 63, w = tid >> 6;
    const int g = l >> 4, i16 = l & 15;
    const int rh = w >> 2, cp = w & 3;
    const int row0 = blockIdx.x * 64;

    __shared__ unsigned short xs[64][72];    //  9.2 KB
    __shared__ unsigned short wt[384][72];   // 55.3 KB (n-major, k inner)

    f32x4 acc[2][6];
    const f32x4 z4 = {0.f, 0.f, 0.f, 0.f};
    for (int rt = 0; rt < 2; ++rt)
        for (int ct = 0; ct < 6; ++ct) acc[rt][ct] = z4;

    const int xrow = tid >> 3, xcol = (tid & 7) * 8;   // x: 2 float4/thread
    const int wn = tid >> 3, wk8 = (tid & 7) * 8;      // W: 6 uint4/thread (n' = wn + it*64)
    const float* xp = &x[(size_t)(row0 + xrow) * 1024 + xcol];
    const unsigned short* wp = &WT[(size_t)wn * 1024 + wk8];

    float4 ax0, ax1, bx0, bx1;
    uint4 aw0, aw1, aw2, aw3, aw4, aw5, bw0, bw1, bw2, bw3, bw4, bw5;

#define QI(k0_, X0, X1, W0, W1, W2, W3, W4, W5) do {                        \
        X0 = *(const float4*)&xp[(k0_)];                                    \
        X1 = *(const float4*)&xp[(k0_) + 4];                                \
        W0 = *(const uint4*)&wp[(k0_)];                                     \
        W1 = *(const uint4*)&wp[64 * 1024 + (k0_)];                         \
        W2 = *(const uint4*)&wp[128 * 1024 + (k0_)];                        \
        W3 = *(const uint4*)&wp[192 * 1024 + (k0_)];                        \
        W4 = *(const uint4*)&wp[256 * 1024 + (k0_)];                        \
        W5 = *(const uint4*)&wp[320 * 1024 + (k0_)];                        \
    } while (0)

#define QS(X0, X1, W0, W1, W2, W3, W4, W5) do {                             \
        *(ushort4*)&xs[xrow][xcol]     = make_ushort4(f2bf(X0.x), f2bf(X0.y), f2bf(X0.z), f2bf(X0.w)); \
        *(ushort4*)&xs[xrow][xcol + 4] = make_ushort4(f2bf(X1.x), f2bf(X1.y), f2bf(X1.z), f2bf(X1.w)); \
        *(uint4*)&wt[wn +   0][wk8] = W0;                                   \
        *(uint4*)&wt[wn +  64][wk8] = W1;                                   \
        *(uint4*)&wt[wn + 128][wk8] = W2;                                   \
        *(uint4*)&wt[wn + 192][wk8] = W3;                                   \
        *(uint4*)&wt[wn + 256][wk8] = W4;                                   \
        *(uint4*)&wt[wn + 320][wk8] = W5;                                   \
    } while (0)

#define QMFMA() do {                                                        \
        bf16x8 af[2][2];                                                    \
        _Pragma("unroll")                                                   \
        for (int rt = 0; rt < 2; ++rt)                                      \
            for (int cc = 0; cc < 2; ++cc)                                  \
                af[rt][cc] = *(const bf16x8*)&xs[rh * 32 + rt * 16 + i16][cc * 32 + 8 * g]; \
        _Pragma("unroll")                                                   \
        for (int ct = 0; ct < 6; ++ct) {                                    \
            _Pragma("unroll")                                               \
            for (int cc = 0; cc < 2; ++cc) {                                \
                bf16x8 bb = *(const bf16x8*)&wt[cp * 96 + ct * 16 + i16][cc * 32 + 8 * g]; \
                for (int rt = 0; rt < 2; ++rt)                              \
                    acc[rt][ct] = __builtin_amdgcn_mfma_f32_16x16x32_bf16(af[rt][cc], bb, acc[rt][ct], 0, 0, 0); \
            }                                                               \
        }                                                                   \
    } while (0)

    QI(0, ax0, ax1, aw0, aw1, aw2, aw3, aw4, aw5);
    QI(64, bx0, bx1, bw0, bw1, bw2, bw3, bw4, bw5);
    #pragma unroll 1
    for (int k0 = 0; k0 < 1024; k0 += 128) {
        __syncthreads();
        QS(ax0, ax1, aw0, aw1, aw2, aw3, aw4, aw5);
        if (k0 + 128 < 1024) QI(k0 + 128, ax0, ax1, aw0, aw1, aw2, aw3, aw4, aw5);
        __syncthreads();
        QMFMA();
        __syncthreads();
        QS(bx0, bx1, bw0, bw1, bw2, bw3, bw4, bw5);
        if (k0 + 192 < 1024) QI(k0 + 192, bx0, bx1, bw0, bw1, bw2, bw3, bw4, bw5);
        __syncthreads();
        QMFMA();
    }
#undef QI
#undef QS
#undef QMFMA

    // epilogue: bounce all 384 cols through LDS (alias over wt)
    __syncthreads();
    unsigned short(*ts)[392] = (unsigned short(*)[392]) & wt[0][0];
    #pragma unroll
    for (int rt = 0; rt < 2; ++rt)
        for (int ct = 0; ct < 6; ++ct) {
            const float sc = (cp * 96 + ct * 16 < 128) ? CEXP : 1.0f;
            for (int r = 0; r < 4; ++r)
                ts[rh * 32 + rt * 16 + g * 4 + r][cp * 96 + ct * 16 + i16] = f2bf(acc[rt][ct][r] * sc);
        }
    __syncthreads();

    const int bq = row0 >> 12;           // batch
    const int s = (row0 >> 6) & 63;      // kv-tile index
    {   // q out (cols 0..127)
        unsigned short* outp = qkv + (size_t)row0 * 128;
        #pragma unroll
        for (int it = 0; it < 2; ++it) {
            int tr = it * 32 + (tid >> 4), dv0 = (tid & 15) * 8;
            *(uint4*)&outp[tr * 128 + dv0] = *(const uint4*)&ts[tr][dv0];
        }
    }
    {   // K frag image (cols 128..255)
        unsigned short* kimg = qkv + K_OFF + ((size_t)(bq * 64 + s) * 2) * 4096;
        #pragma unroll
        for (int it = 0; it < 2; ++it) {
            int lin = it * 512 + tid;      // 0..1023
            int branch_ = (lin >> 9) & 1;
            int region = (lin >> 6) & 7;
            int slot = lin & 63;
            int row = (region >> 1) * 16 + (slot & 15);
            int d = 128 + branch_ * 64 + (region & 1) * 32 + (slot >> 4) * 8;
            uint4 vv = *(const uint4*)&ts[row][d];
            *(uint4*)&kimg[(size_t)branch_ * 4096 + (region * 64 + slot) * 8] = vv;
        }
    }
    {   // V frag image (cols 256..383)
        unsigned short* vimg = qkv + VT_OFF + (size_t)(bq * 64 + s) * 8192;
        #pragma unroll
        for (int it = 0; it < 2; ++it) {
            int lin = it * 512 + tid;      // 0..1023
            int region = (lin >> 6) & 15;
            int slot = lin & 63;
            int dv = 256 + (region >> 1) * 16 + (slot & 15);
            int kv0 = (region & 1) * 32 + (slot >> 4) * 8;
            unsigned short tmp[8];
            #pragma unroll
            for (int e = 0; e < 8; ++e) tmp[e] = ts[kv0 + e][dv];
            *(uint4*)&vimg[(region * 64 + slot) * 8] = *(uint4*)tmp;
        }
    }
}

// ---------------- Differential causal flash attention, paired rows ----------------
// grid (32, 4, nc*2): z = c*2+branch, nc = 4. Block owns adjacent row PAIR
// (t_e, t_o); COMPLEMENT SWIZZLE bxe = (c&1)?31-bx:bx balances CU totals.
// FUSED QK: each kf read once, 2 MFMA (A,B). DOUBLE-BUFFERED ksf -> 2
// barriers/tile. Q pre-scaled by CEXP; p = exp2(S'). PV: V in registers,
// dv-split, psf 16KB. LDS = 32KB. Empty chunks return; combine skips.
__global__ __launch_bounds__(256, 3) void diff_attn_pair(
    const unsigned short* __restrict__ q, const unsigned short* __restrict__ kimg,
    const unsigned short* __restrict__ vimg,
    float* __restrict__ part, int ncs) {
    const int bx = blockIdx.x, b = blockIdx.y;
    const int c = blockIdx.z >> 1, branch = blockIdx.z & 1;
    const int bxe = (c & 1) ? (31 - bx) : bx;
    const int t_o = 63 - 2 * bxe, t_e = t_o - 1;
    const int n = t_o + 1;
    const int s_lo = (c * n) >> ncs, smax = ((c + 1) * n) >> ncs;

    if (s_lo >= smax) return;

    const int tid = threadIdx.x;
    const int l = tid & 63, w = tid >> 6;
    const int gq = l >> 4, i16 = l & 15;
    const float NEGINF = -__builtin_inff();

    __shared__ unsigned short ksf[2][4096];
    __shared__ unsigned short psf[8192];

    float* recA = part + ((((size_t)(b * 64 + t_e) << ncs) + c) * 2 + branch) * REC_FLOATS;
    float* recB = part + ((((size_t)(b * 64 + t_o) << ncs) + c) * 2 + branch) * REC_FLOATS;
    const bool emptyA = (s_lo > t_e);

    const size_t bbase = (size_t)b * 4096;
    const unsigned short* kimg_b = kimg + (size_t)b * 524288;
    const unsigned short* vimg_b = vimg + (size_t)b * 524288;
    const int tid8 = tid * 8;
    const int l8 = l * 8;
    const f32x4 z4 = {0.f, 0.f, 0.f, 0.f};

    bf16x8 qfA[2], qfB[2];
    #pragma unroll
    for (int cc = 0; cc < 2; ++cc) {
        qfA[cc] = *(const bf16x8*)&q[(bbase + t_e * 64 + w * 16 + i16) * 128 + branch * 64 + cc * 32 + 8 * gq];
        qfB[cc] = *(const bf16x8*)&q[(bbase + t_o * 64 + w * 16 + i16) * 128 + branch * 64 + cc * 32 + 8 * gq];
    }

    float lsumA = 0.f, lsumB = 0.f;
    f32x4 acc[2][4][2];
    for (int qs = 0; qs < 2; ++qs)
        for (int qg = 0; qg < 4; ++qg)
            for (int j = 0; j < 2; ++j) acc[qs][qg][j] = z4;

    int pdst[4];
    #pragma unroll
    for (int cb = 0; cb < 4; ++cb)
        pdst[cb] = ((w * 2 + (cb >> 1)) * 64 + ((cb & 1) * 2 + (gq >> 1)) * 16 + i16) * 8 + (gq & 1) * 4;

    uint4 kr0, kr1;
    bf16x8 vb00, vb01, vb10, vb11;

#define K_ISSUE(s_) do {                                                            \
        const unsigned short* kp = &kimg_b[((size_t)(s_) * 2 + branch) * 4096];     \
        kr0 = *(const uint4*)&kp[tid8];                                             \
        kr1 = *(const uint4*)&kp[tid8 + 2048];                                      \
    } while (0)
#define V_ISSUE(s_) do {                                                            \
        const unsigned short* vp = &vimg_b[(size_t)(s_) * 8192 + w * 2048];         \
        vb00 = *(const bf16x8*)&vp[l8];                                             \
        vb01 = *(const bf16x8*)&vp[512 + l8];                                       \
        vb10 = *(const bf16x8*)&vp[1024 + l8];                                      \
        vb11 = *(const bf16x8*)&vp[1536 + l8];                                      \
    } while (0)

    K_ISSUE(s_lo);
    V_ISSUE(s_lo);
    int pb = 0;
    #pragma unroll 1
    for (int s = s_lo; s < smax; ++s) {
        *(uint4*)&ksf[pb][tid8] = kr0;
        *(uint4*)&ksf[pb][tid8 + 2048] = kr1;
        if (s + 1 < smax) K_ISSUE(s + 1);
        __syncthreads();   // merged: ksf[pb] ready + prev PV done reading psf
        const bool aAct = (s != t_o);

        f32x4 scA[4], scB[4];
        for (int cb = 0; cb < 4; ++cb) { scA[cb] = z4; scB[cb] = z4; }
        __builtin_amdgcn_s_setprio(1);
        #pragma unroll
        for (int cb = 0; cb < 4; ++cb)
            for (int cc = 0; cc < 2; ++cc) {
                bf16x8 kf = *(const bf16x8*)&ksf[pb][((cb * 2 + cc) * 64 + l) * 8];
                scA[cb] = __builtin_amdgcn_mfma_f32_16x16x32_bf16(kf, qfA[cc], scA[cb], 0, 0, 0);
                scB[cb] = __builtin_amdgcn_mfma_f32_16x16x32_bf16(kf, qfB[cc], scB[cb], 0, 0, 0);
            }
        __builtin_amdgcn_s_setprio(0);

        if (aAct) {
            if (s == t_e) {
                int ql = w * 16 + i16;
                for (int cb = 0; cb < 4; ++cb)
                    for (int r = 0; r < 4; ++r)
                        if (cb * 16 + gq * 4 + r > ql) scA[cb][r] = NEGINF;
            }
            #pragma unroll
            for (int cb = 0; cb < 4; ++cb) {
                float p0 = exp2f(scA[cb][0]);
                float p1 = exp2f(scA[cb][1]);
                float p2 = exp2f(scA[cb][2]);
                float p3 = exp2f(scA[cb][3]);
                lsumA += (p0 + p1) + (p2 + p3);
                uint2 pw;
                pw.x = cvt_pk_bf16(p0, p1);
                pw.y = cvt_pk_bf16(p2, p3);
                *(uint2*)&psf[pdst[cb]] = pw;
            }
        }
        {
            if (s == t_o) {
                int ql = w * 16 + i16;
                for (int cb = 0; cb < 4; ++cb)
                    for (int r = 0; r < 4; ++r)
                        if (cb * 16 + gq * 4 + r > ql) scB[cb][r] = NEGINF;
            }
            #pragma unroll
            for (int cb = 0; cb < 4; ++cb) {
                float p0 = exp2f(scB[cb][0]);
                float p1 = exp2f(scB[cb][1]);
                float p2 = exp2f(scB[cb][2]);
                float p3 = exp2f(scB[cb][3]);
                lsumB += (p0 + p1) + (p2 + p3);
                uint2 pw;
                pw.x = cvt_pk_bf16(p0, p1);
                pw.y = cvt_pk_bf16(p2, p3);
                *(uint2*)&psf[4096 + pdst[cb]] = pw;
            }
        }
        __syncthreads();   // psf complete

        __builtin_amdgcn_s_setprio(1);
        if (aAct) {
            #pragma unroll
            for (int qg = 0; qg < 4; ++qg) {
                bf16x8 pa0 = *(const bf16x8*)&psf[(qg * 2 + 0) * 512 + l8];
                bf16x8 pa1 = *(const bf16x8*)&psf[(qg * 2 + 1) * 512 + l8];
                acc[0][qg][0] = __builtin_amdgcn_mfma_f32_16x16x32_bf16(pa0, vb00, acc[0][qg][0], 0, 0, 0);
                acc[0][qg][0] = __builtin_amdgcn_mfma_f32_16x16x32_bf16(pa1, vb01, acc[0][qg][0], 0, 0, 0);
                acc[0][qg][1] = __builtin_amdgcn_mfma_f32_16x16x32_bf16(pa0, vb10, acc[0][qg][1], 0, 0, 0);
                acc[0][qg][1] = __builtin_amdgcn_mfma_f32_16x16x32_bf16(pa1, vb11, acc[0][qg][1], 0, 0, 0);
            }
        }
        #pragma unroll
        for (int qg = 0; qg < 4; ++qg) {
            bf16x8 pa0 = *(const bf16x8*)&psf[4096 + (qg * 2 + 0) * 512 + l8];
            bf16x8 pa1 = *(const bf16x8*)&psf[4096 + (qg * 2 + 1) * 512 + l8];
            acc[1][qg][0] = __builtin_amdgcn_mfma_f32_16x16x32_bf16(pa0, vb00, acc[1][qg][0], 0, 0, 0);
            acc[1][qg][0] = __builtin_amdgcn_mfma_f32_16x16x32_bf16(pa1, vb01, acc[1][qg][0], 0, 0, 0);
            acc[1][qg][1] = __builtin_amdgcn_mfma_f32_16x16x32_bf16(pa0, vb10, acc[1][qg][1], 0, 0, 0);
            acc[1][qg][1] = __builtin_amdgcn_mfma_f32_16x16x32_bf16(pa1, vb11, acc[1][qg][1], 0, 0, 0);
        }
        __builtin_amdgcn_s_setprio(0);
        if (s + 1 < smax) V_ISSUE(s + 1);
        pb ^= 1;
    }
#undef K_ISSUE
#undef V_ISSUE

    lsumA += __shfl_xor(lsumA, 16);
    lsumA += __shfl_xor(lsumA, 32);
    lsumB += __shfl_xor(lsumB, 16);
    lsumB += __shfl_xor(lsumB, 32);
    if (!emptyA) {
        if (gq == 0) recA[w * 16 + i16] = lsumA;
        unsigned short* OA = (unsigned short*)(recA + 64);
        for (int qg = 0; qg < 4; ++qg)
            for (int j = 0; j < 2; ++j)
                for (int r = 0; r < 4; ++r)
                    OA[(qg * 16 + gq * 4 + r) * 128 + (w * 2 + j) * 16 + i16] = f2bf(acc[0][qg][j][r]);
    }
    {
        if (gq == 0) recB[w * 16 + i16] = lsumB;
        unsigned short* OB = (unsigned short*)(recB + 64);
        for (int qg = 0; qg < 4; ++qg)
            for (int j = 0; j < 2; ++j)
                for (int r = 0; r < 4; ++r)
                    OB[(qg * 16 + gq * 4 + r) * 128 + (w * 2 + j) * 16 + i16] = f2bf(acc[1][qg][j][r]);
    }
}

// ---------------- combine: sum valid chunks per branch, normalize, o1 - lam*o2 ----------
__global__ __launch_bounds__(256) void diff_combine(
    const float* __restrict__ part,
    const float* __restrict__ lq1, const float* __restrict__ lq2,
    const float* __restrict__ lk1, const float* __restrict__ lk2,
    float* __restrict__ out, int ncs) {
    const int t = blockIdx.x, b = blockIdx.y;
    const int tid = threadIdx.x;
    const int nc = 1 << ncs;
    const int n = (t | 1) + 1;
    __shared__ float sl[2][64];
    __shared__ float s_lam;

    const float* recbase = part + (((size_t)(b * 64 + t) << ncs)) * 2 * REC_FLOATS;

    if (tid < 64) {
        float s1 = lq1[tid] * lk1[tid];
        float s2 = lq2[tid] * lk2[tid];
        for (int off = 32; off > 0; off >>= 1) {
            s1 += __shfl_xor(s1, off);
            s2 += __shfl_xor(s2, off);
        }
        if (tid == 0) s_lam = expf(s1) - expf(s2) + LAMBDA_INIT;
    }
    if (tid < 128) {
        int r = tid & 63, br = tid >> 6;
        float acc = 0.f;
        for (int c = 0; c < nc; ++c) {
            int lo = (c * n) >> ncs, hi = ((c + 1) * n) >> ncs;
            if (lo >= hi || lo > t) continue;
            acc += recbase[(c * 2 + br) * REC_FLOATS + r];
        }
        sl[br][r] = acc;
    }
    __syncthreads();
    const float lam = s_lam;

    float* op = out + ((size_t)b * 4096 + (size_t)t * 64) * 128;
    for (int grp = 0; grp < 4; ++grp) {
        int gid = grp * 256 + tid;
        int e = gid * 8;
        int row = e >> 7;
        float o1[8] = {0, 0, 0, 0, 0, 0, 0, 0}, o2[8] = {0, 0, 0, 0, 0, 0, 0, 0};
        for (int c = 0; c < nc; ++c) {
            int lo = (c * n) >> ncs, hi = ((c + 1) * n) >> ncs;
            if (lo >= hi || lo > t) continue;
            const unsigned short* O0 = (const unsigned short*)(recbase + (c * 2 + 0) * REC_FLOATS + 64);
            const unsigned short* O1 = (const unsigned short*)(recbase + (c * 2 + 1) * REC_FLOATS + 64);
            uint4 u0 = *(const uint4*)&O0[e];
            uint4 u1 = *(const uint4*)&O1[e];
            const unsigned short* e0 = (const unsigned short*)&u0;
            const unsigned short* e1 = (const unsigned short*)&u1;
            #pragma unroll
            for (int j = 0; j < 8; ++j) {
                o1[j] += bf2f(e0[j]);
                o2[j] += bf2f(e1[j]);
            }
        }
        float l1inv = 1.0f / sl[0][row], l2inv = 1.0f / sl[1][row];
        float res[8];
        #pragma unroll
        for (int j = 0; j < 8; ++j) res[j] = o1[j] * l1inv - lam * o2[j] * l2inv;
        *(float4*)&op[e] = *(float4*)&res[0];
        *(float4*)&op[e + 4] = *(float4*)&res[4];
    }
}

extern "C" void kernel_launch(void* const* d_in, const int* in_sizes, int n_in,
                              void* d_out, int out_size, void* d_ws, size_t ws_size,
                              hipStream_t stream) {
    const float* x   = (const float*)d_in[0];
    const float* Wq  = (const float*)d_in[1];
    const float* Wk  = (const float*)d_in[2];
    const float* Wv  = (const float*)d_in[3];
    const float* lq1 = (const float*)d_in[4];
    const float* lq2 = (const float*)d_in[5];
    const float* lk1 = (const float*)d_in[6];
    const float* lk2 = (const float*)d_in[7];
    float* out = (float*)d_out;
    unsigned short* qkv = (unsigned short*)d_ws;

    const int ncs = 2;  // 4 kv-chunks
    const size_t part_bytes = (size_t)256 * (1 << ncs) * 2 * REC_FLOATS * 4;
    float* part = (float*)((char*)d_ws + PART_OFF_BYTES);
    unsigned short* WT = (unsigned short*)((char*)d_ws + PART_OFF_BYTES + part_bytes);

    prep_wt<<<dim3(16, 2, 3), 256, 0, stream>>>(Wq, Wk, Wv, WT);
    qkv_fused<<<256, 512, 0, stream>>>(x, WT, qkv);

    const unsigned short* qb = qkv;
    const unsigned short* kb = qkv + K_OFF;
    const unsigned short* vtb = qkv + VT_OFF;
    diff_attn_pair<<<dim3(32, 4, 2 << ncs), 256, 0, stream>>>(qb, kb, vtb, part, ncs);
    diff_combine<<<dim3(64, 4), 256, 0, stream>>>(part, lq1, lq2, lk1, lk2, out, ncs);
}

// Round 19
// 91.840 us; speedup vs baseline: 1.0652x; 1.0115x over previous
//
#include <hip/hip_runtime.h>
#include <hip/hip_bf16.h>

typedef __bf16 bf16x8 __attribute__((ext_vector_type(8)));
typedef float f32x4 __attribute__((ext_vector_type(4)));

#define LAMBDA_INIT 0.3555090675909693f
#define CEXP 0.18033688011112042f   // 0.125 * log2(e), folded into Q at projection

// ws layout (bytes):
//  q    : [0, 4.19M)       bf16 [16384][128] row-major, PRE-SCALED by CEXP
//  kimg : [4.19M, 8.39M)   bf16 [4][64][2][8 regions][64 slots][8]  (frag image)
//  vimg : [8.39M, 12.58M)  bf16 [4][64][16 regions][64 slots][8]    (frag image)
//  part : [12.58M, +34.1M) recs x 16640B (l[64] f32 + O[64][128] bf16)
//  WT   : after part       bf16 W'[384][1024]
#define K_OFF   ((size_t)16384 * 128)
#define VT_OFF  ((size_t)2 * 16384 * 128)
#define PART_OFF_BYTES ((size_t)12582912)
#define REC_FLOATS 4160  // 64 l + 4096 words of bf16 O

__device__ __forceinline__ unsigned short f2bf(float f) {
    __hip_bfloat16 h = __float2bfloat16(f);
    unsigned short u;
    __builtin_memcpy(&u, &h, 2);
    return u;
}
__device__ __forceinline__ float bf2f(unsigned short u) {
    unsigned int x = ((unsigned int)u) << 16;
    float f;
    __builtin_memcpy(&f, &x, 4);
    return f;
}
__device__ __forceinline__ unsigned int cvt_pk_bf16(float a, float b) {
    unsigned int r;
    asm volatile("v_cvt_pk_bf16_f32 %0, %1, %2" : "=v"(r) : "v"(a), "v"(b));
    return r;
}

// ---------------- W pre-transpose: [1024][128] f32 -> [128][1024] bf16 ----------------
__global__ __launch_bounds__(256) void prep_wt(
    const float* __restrict__ Wq, const float* __restrict__ Wk,
    const float* __restrict__ Wv, unsigned short* __restrict__ WT) {
    const int kt = blockIdx.x, nt = blockIdx.y, mat = blockIdx.z;
    const float* W = (mat == 0) ? Wq : (mat == 1) ? Wk : Wv;
    unsigned short* O = WT + (size_t)mat * 128 * 1024;
    __shared__ float tb[64][65];
    const int r = threadIdx.x >> 2, c4 = (threadIdx.x & 3) * 16;
    for (int j = 0; j < 4; ++j) {
        float4 v = *(const float4*)&W[(size_t)(kt * 64 + r) * 128 + nt * 64 + c4 + j * 4];
        tb[r][c4 + j * 4 + 0] = v.x;
        tb[r][c4 + j * 4 + 1] = v.y;
        tb[r][c4 + j * 4 + 2] = v.z;
        tb[r][c4 + j * 4 + 3] = v.w;
    }
    __syncthreads();
    unsigned short tmp[16];
    for (int j = 0; j < 16; ++j) tmp[j] = f2bf(tb[c4 + j][r]);
    *(uint4*)&O[(size_t)(nt * 64 + r) * 1024 + kt * 64 + c4] = *(uint4*)&tmp[0];
    *(uint4*)&O[(size_t)(nt * 64 + r) * 1024 + kt * 64 + c4 + 8] = *(uint4*)&tmp[8];
}

// ---------------- Fused QKV GEMM, N-split: grid (256 row-tiles, 2 N-halves) ----------
// Linear ids i and i+256 land on the SAME CU -> the two N-halves of a row-tile
// share the x tile via L2 (x read once from HBM). 2 blocks x 512 thr = 16
// waves/CU (the single-grid version ran 8). Wave (rh=w>>2, cp=w&3): rows
// rh*32+[0,32), local cols cp*48+[0,48). W half k-slice (192x64) staged per
// k-step (L2-resident). 1-deep named-reg prefetch.
// np=0 -> q (CEXP-scaled) + K-branch0 frag image; np=1 -> K-branch1 + V image.
__global__ __launch_bounds__(512) void qkv_fused(
    const float* __restrict__ x, const unsigned short* __restrict__ WT,
    unsigned short* __restrict__ qkv) {
    const int tid = threadIdx.x;
    const int l = tid & 63, w = tid >> 6;
    const int g = l >> 4, i16 = l & 15;
    const int rh = w >> 2, cp = w & 3;
    const int row0 = blockIdx.x * 64;
    const int np = blockIdx.y;
    const unsigned short* Wt = WT + (size_t)np * 192 * 1024;

    __shared__ unsigned short xs[64][72];    //  9.2 KB
    __shared__ unsigned short wt[192][72];   // 27.6 KB

    f32x4 acc[2][3];
    const f32x4 z4 = {0.f, 0.f, 0.f, 0.f};
    for (int rt = 0; rt < 2; ++rt)
        for (int ct = 0; ct < 3; ++ct) acc[rt][ct] = z4;

    const int xrow = tid >> 3, xcol = (tid & 7) * 8;   // x: 2 float4/thread
    const int wn = tid >> 3, wk8 = (tid & 7) * 8;      // W: 3 uint4/thread
    const float* xp = &x[(size_t)(row0 + xrow) * 1024 + xcol];
    const unsigned short* wp = &Wt[(size_t)wn * 1024 + wk8];

    float4 ax0, ax1;
    uint4 aw0, aw1, aw2;

#define QI(k0_) do {                                                        \
        ax0 = *(const float4*)&xp[(k0_)];                                   \
        ax1 = *(const float4*)&xp[(k0_) + 4];                               \
        aw0 = *(const uint4*)&wp[(k0_)];                                    \
        aw1 = *(const uint4*)&wp[64 * 1024 + (k0_)];                        \
        aw2 = *(const uint4*)&wp[128 * 1024 + (k0_)];                       \
    } while (0)

#define QS() do {                                                           \
        *(ushort4*)&xs[xrow][xcol]     = make_ushort4(f2bf(ax0.x), f2bf(ax0.y), f2bf(ax0.z), f2bf(ax0.w)); \
        *(ushort4*)&xs[xrow][xcol + 4] = make_ushort4(f2bf(ax1.x), f2bf(ax1.y), f2bf(ax1.z), f2bf(ax1.w)); \
        *(uint4*)&wt[wn +   0][wk8] = aw0;                                  \
        *(uint4*)&wt[wn +  64][wk8] = aw1;                                  \
        *(uint4*)&wt[wn + 128][wk8] = aw2;                                  \
    } while (0)

    QI(0);
    #pragma unroll 1
    for (int k0 = 0; k0 < 1024; k0 += 64) {
        __syncthreads();
        QS();
        if (k0 + 64 < 1024) QI(k0 + 64);
        __syncthreads();
        bf16x8 af[2][2];
        #pragma unroll
        for (int rt = 0; rt < 2; ++rt)
            for (int cc = 0; cc < 2; ++cc)
                af[rt][cc] = *(const bf16x8*)&xs[rh * 32 + rt * 16 + i16][cc * 32 + 8 * g];
        #pragma unroll
        for (int ct = 0; ct < 3; ++ct)
            for (int cc = 0; cc < 2; ++cc) {
                bf16x8 bb = *(const bf16x8*)&wt[cp * 48 + ct * 16 + i16][cc * 32 + 8 * g];
                for (int rt = 0; rt < 2; ++rt)
                    acc[rt][ct] = __builtin_amdgcn_mfma_f32_16x16x32_bf16(af[rt][cc], bb, acc[rt][ct], 0, 0, 0);
            }
    }
#undef QI
#undef QS

    // epilogue: bounce 192 local cols through LDS (alias over wt)
    __syncthreads();
    unsigned short(*ts)[200] = (unsigned short(*)[200]) & wt[0][0];
    #pragma unroll
    for (int rt = 0; rt < 2; ++rt)
        for (int ct = 0; ct < 3; ++ct) {
            const float sc = (np == 0 && cp * 48 + ct * 16 < 128) ? CEXP : 1.0f;
            for (int r = 0; r < 4; ++r)
                ts[rh * 32 + rt * 16 + g * 4 + r][cp * 48 + ct * 16 + i16] = f2bf(acc[rt][ct][r] * sc);
        }
    __syncthreads();

    const int bq = row0 >> 12;
    const int s = (row0 >> 6) & 63;
    if (np == 0) {
        {   // q out (local cols 0..127)
            unsigned short* outp = qkv + (size_t)row0 * 128;
            #pragma unroll
            for (int it = 0; it < 2; ++it) {
                int tr = it * 32 + (tid >> 4), dv0 = (tid & 15) * 8;
                *(uint4*)&outp[tr * 128 + dv0] = *(const uint4*)&ts[tr][dv0];
            }
        }
        {   // K branch-0 image (local cols 128..191)
            unsigned short* kimg = qkv + K_OFF + ((size_t)(bq * 64 + s) * 2) * 4096;
            int region = tid >> 6, slot = tid & 63;
            int row = (region >> 1) * 16 + (slot & 15);
            int d = 128 + (region & 1) * 32 + (slot >> 4) * 8;
            uint4 vv = *(const uint4*)&ts[row][d];
            *(uint4*)&kimg[(region * 64 + slot) * 8] = vv;
        }
    } else {
        {   // K branch-1 image (local cols 0..63)
            unsigned short* kimg = qkv + K_OFF + ((size_t)(bq * 64 + s) * 2 + 1) * 4096;
            int region = tid >> 6, slot = tid & 63;
            int row = (region >> 1) * 16 + (slot & 15);
            int d = (region & 1) * 32 + (slot >> 4) * 8;
            uint4 vv = *(const uint4*)&ts[row][d];
            *(uint4*)&kimg[(region * 64 + slot) * 8] = vv;
        }
        {   // V image (local cols 64..191)
            unsigned short* vimg = qkv + VT_OFF + (size_t)(bq * 64 + s) * 8192;
            #pragma unroll
            for (int it = 0; it < 2; ++it) {
                int lin = it * 512 + tid;
                int region = lin >> 6, slot = lin & 63;
                int dv = 64 + (region >> 1) * 16 + (slot & 15);
                int kv0 = (region & 1) * 32 + (slot >> 4) * 8;
                unsigned short tmp[8];
                #pragma unroll
                for (int e = 0; e < 8; ++e) tmp[e] = ts[kv0 + e][dv];
                *(uint4*)&vimg[(region * 64 + slot) * 8] = *(uint4*)tmp;
            }
        }
    }
}

// ---------------- Differential causal flash attention, single-barrier pipeline ------
// grid (32, 4, 8): z = c*2+branch, nc=4 chunks. Paired rows (t_e, t_o),
// COMPLEMENT SWIZZLE bxe = (c&1)?31-bx:bx.
// ONE barrier per tile: [store ksf[s&1]; issue K(s+1)] -> barrier ->
// MFMA cluster {PV(s-1) from psf[(s-1)&1] || QK(s) from ksf[s&1]} ->
// issue V(s) -> SM(s) writes psf[s&1]. Drain: barrier + PV(smax-1).
// Hazards: ksf[s&1] store vs QK(s-2) reads: 2 barriers apart. SM(s) write of
// psf[s&1] vs PV(s-2) reads of same buffer: separated by barrier(s).
// LDS = 48KB (ksf 2x8K + psf 2x16K) -> 3 blocks/CU resident + backfill.
__global__ __launch_bounds__(256, 3) void diff_attn_pair(
    const unsigned short* __restrict__ q, const unsigned short* __restrict__ kimg,
    const unsigned short* __restrict__ vimg,
    float* __restrict__ part, int ncs) {
    const int bx = blockIdx.x, b = blockIdx.y;
    const int c = blockIdx.z >> 1, branch = blockIdx.z & 1;
    const int bxe = (c & 1) ? (31 - bx) : bx;
    const int t_o = 63 - 2 * bxe, t_e = t_o - 1;
    const int n = t_o + 1;
    const int s_lo = (c * n) >> ncs, smax = ((c + 1) * n) >> ncs;

    if (s_lo >= smax) return;

    const int tid = threadIdx.x;
    const int l = tid & 63, w = tid >> 6;
    const int gq = l >> 4, i16 = l & 15;
    const float NEGINF = -__builtin_inff();

    __shared__ unsigned short ksf[2][4096];   // 16 KB K frag image, dbuf
    __shared__ unsigned short psf[2][8192];   // 32 KB P (both qsets), dbuf

    float* recA = part + ((((size_t)(b * 64 + t_e) << ncs) + c) * 2 + branch) * REC_FLOATS;
    float* recB = part + ((((size_t)(b * 64 + t_o) << ncs) + c) * 2 + branch) * REC_FLOATS;
    const bool emptyA = (s_lo > t_e);

    const size_t bbase = (size_t)b * 4096;
    const unsigned short* kimg_b = kimg + (size_t)b * 524288;
    const unsigned short* vimg_b = vimg + (size_t)b * 524288;
    const int tid8 = tid * 8;
    const int l8 = l * 8;
    const f32x4 z4 = {0.f, 0.f, 0.f, 0.f};

    bf16x8 qfA[2], qfB[2];
    #pragma unroll
    for (int cc = 0; cc < 2; ++cc) {
        qfA[cc] = *(const bf16x8*)&q[(bbase + t_e * 64 + w * 16 + i16) * 128 + branch * 64 + cc * 32 + 8 * gq];
        qfB[cc] = *(const bf16x8*)&q[(bbase + t_o * 64 + w * 16 + i16) * 128 + branch * 64 + cc * 32 + 8 * gq];
    }

    float lsumA = 0.f, lsumB = 0.f;
    f32x4 acc[2][4][2];
    for (int qs = 0; qs < 2; ++qs)
        for (int qg = 0; qg < 4; ++qg)
            for (int j = 0; j < 2; ++j) acc[qs][qg][j] = z4;

    int pdst[4];
    #pragma unroll
    for (int cb = 0; cb < 4; ++cb)
        pdst[cb] = ((w * 2 + (cb >> 1)) * 64 + ((cb & 1) * 2 + (gq >> 1)) * 16 + i16) * 8 + (gq & 1) * 4;

    uint4 kr0, kr1;
    bf16x8 vb00, vb01, vb10, vb11;

#define K_ISSUE(s_) do {                                                            \
        const unsigned short* kp = &kimg_b[((size_t)(s_) * 2 + branch) * 4096];     \
        kr0 = *(const uint4*)&kp[tid8];                                             \
        kr1 = *(const uint4*)&kp[tid8 + 2048];                                      \
    } while (0)
#define V_ISSUE(s_) do {                                                            \
        const unsigned short* vp = &vimg_b[(size_t)(s_) * 8192 + w * 2048];         \
        vb00 = *(const bf16x8*)&vp[l8];                                             \
        vb01 = *(const bf16x8*)&vp[512 + l8];                                       \
        vb10 = *(const bf16x8*)&vp[1024 + l8];                                      \
        vb11 = *(const bf16x8*)&vp[1536 + l8];                                      \
    } while (0)

#define PV_CLUSTER(pp_, aPrev_) do {                                                \
        if (aPrev_) {                                                               \
            _Pragma("unroll")                                                       \
            for (int qg = 0; qg < 4; ++qg) {                                        \
                bf16x8 pa0 = *(const bf16x8*)&psf[pp_][(qg * 2 + 0) * 512 + l8];    \
                bf16x8 pa1 = *(const bf16x8*)&psf[pp_][(qg * 2 + 1) * 512 + l8];    \
                acc[0][qg][0] = __builtin_amdgcn_mfma_f32_16x16x32_bf16(pa0, vb00, acc[0][qg][0], 0, 0, 0); \
                acc[0][qg][0] = __builtin_amdgcn_mfma_f32_16x16x32_bf16(pa1, vb01, acc[0][qg][0], 0, 0, 0); \
                acc[0][qg][1] = __builtin_amdgcn_mfma_f32_16x16x32_bf16(pa0, vb10, acc[0][qg][1], 0, 0, 0); \
                acc[0][qg][1] = __builtin_amdgcn_mfma_f32_16x16x32_bf16(pa1, vb11, acc[0][qg][1], 0, 0, 0); \
            }                                                                       \
        }                                                                           \
        _Pragma("unroll")                                                           \
        for (int qg = 0; qg < 4; ++qg) {                                            \
            bf16x8 pa0 = *(const bf16x8*)&psf[pp_][4096 + (qg * 2 + 0) * 512 + l8]; \
            bf16x8 pa1 = *(const bf16x8*)&psf[pp_][4096 + (qg * 2 + 1) * 512 + l8]; \
            acc[1][qg][0] = __builtin_amdgcn_mfma_f32_16x16x32_bf16(pa0, vb00, acc[1][qg][0], 0, 0, 0); \
            acc[1][qg][0] = __builtin_amdgcn_mfma_f32_16x16x32_bf16(pa1, vb01, acc[1][qg][0], 0, 0, 0); \
            acc[1][qg][1] = __builtin_amdgcn_mfma_f32_16x16x32_bf16(pa0, vb10, acc[1][qg][1], 0, 0, 0); \
            acc[1][qg][1] = __builtin_amdgcn_mfma_f32_16x16x32_bf16(pa1, vb11, acc[1][qg][1], 0, 0, 0); \
        }                                                                           \
    } while (0)

    K_ISSUE(s_lo);
    #pragma unroll 1
    for (int s = s_lo; s < smax; ++s) {
        const int kb = s & 1;
        *(uint4*)&ksf[kb][tid8] = kr0;
        *(uint4*)&ksf[kb][tid8 + 2048] = kr1;
        if (s + 1 < smax) K_ISSUE(s + 1);
        __syncthreads();   // the ONE barrier: ksf[kb] ready; prev SM's psf visible

        __builtin_amdgcn_s_setprio(1);
        if (s > s_lo) PV_CLUSTER((s - 1) & 1, (s - 1) != t_o);
        f32x4 scA[4], scB[4];
        for (int cb = 0; cb < 4; ++cb) { scA[cb] = z4; scB[cb] = z4; }
        #pragma unroll
        for (int cb = 0; cb < 4; ++cb)
            for (int cc = 0; cc < 2; ++cc) {
                bf16x8 kf = *(const bf16x8*)&ksf[kb][((cb * 2 + cc) * 64 + l) * 8];
                scA[cb] = __builtin_amdgcn_mfma_f32_16x16x32_bf16(kf, qfA[cc], scA[cb], 0, 0, 0);
                scB[cb] = __builtin_amdgcn_mfma_f32_16x16x32_bf16(kf, qfB[cc], scB[cb], 0, 0, 0);
            }
        __builtin_amdgcn_s_setprio(0);
        V_ISSUE(s);        // vb free (PV(s-1) consumed); flight = SM + barrier

        // ---- SM(s) -> psf[s&1] ----
        const bool aAct = (s != t_o);
        if (aAct) {
            if (s == t_e) {
                int ql = w * 16 + i16;
                for (int cb = 0; cb < 4; ++cb)
                    for (int r = 0; r < 4; ++r)
                        if (cb * 16 + gq * 4 + r > ql) scA[cb][r] = NEGINF;
            }
            #pragma unroll
            for (int cb = 0; cb < 4; ++cb) {
                float p0 = exp2f(scA[cb][0]);
                float p1 = exp2f(scA[cb][1]);
                float p2 = exp2f(scA[cb][2]);
                float p3 = exp2f(scA[cb][3]);
                lsumA += (p0 + p1) + (p2 + p3);
                uint2 pw;
                pw.x = cvt_pk_bf16(p0, p1);
                pw.y = cvt_pk_bf16(p2, p3);
                *(uint2*)&psf[kb][pdst[cb]] = pw;
            }
        }
        {
            if (s == t_o) {
                int ql = w * 16 + i16;
                for (int cb = 0; cb < 4; ++cb)
                    for (int r = 0; r < 4; ++r)
                        if (cb * 16 + gq * 4 + r > ql) scB[cb][r] = NEGINF;
            }
            #pragma unroll
            for (int cb = 0; cb < 4; ++cb) {
                float p0 = exp2f(scB[cb][0]);
                float p1 = exp2f(scB[cb][1]);
                float p2 = exp2f(scB[cb][2]);
                float p3 = exp2f(scB[cb][3]);
                lsumB += (p0 + p1) + (p2 + p3);
                uint2 pw;
                pw.x = cvt_pk_bf16(p0, p1);
                pw.y = cvt_pk_bf16(p2, p3);
                *(uint2*)&psf[kb][4096 + pdst[cb]] = pw;
            }
        }
    }

    // drain: last tile's PV (psf written by all waves -> barrier first)
    __syncthreads();
    __builtin_amdgcn_s_setprio(1);
    PV_CLUSTER((smax - 1) & 1, (smax - 1) != t_o);
    __builtin_amdgcn_s_setprio(0);
#undef K_ISSUE
#undef V_ISSUE
#undef PV_CLUSTER

    // flush
    lsumA += __shfl_xor(lsumA, 16);
    lsumA += __shfl_xor(lsumA, 32);
    lsumB += __shfl_xor(lsumB, 16);
    lsumB += __shfl_xor(lsumB, 32);
    if (!emptyA) {
        if (gq == 0) recA[w * 16 + i16] = lsumA;
        unsigned short* OA = (unsigned short*)(recA + 64);
        for (int qg = 0; qg < 4; ++qg)
            for (int j = 0; j < 2; ++j)
                for (int r = 0; r < 4; ++r)
                    OA[(qg * 16 + gq * 4 + r) * 128 + (w * 2 + j) * 16 + i16] = f2bf(acc[0][qg][j][r]);
    }
    {
        if (gq == 0) recB[w * 16 + i16] = lsumB;
        unsigned short* OB = (unsigned short*)(recB + 64);
        for (int qg = 0; qg < 4; ++qg)
            for (int j = 0; j < 2; ++j)
                for (int r = 0; r < 4; ++r)
                    OB[(qg * 16 + gq * 4 + r) * 128 + (w * 2 + j) * 16 + i16] = f2bf(acc[1][qg][j][r]);
    }
}

// ---------------- combine: sum valid chunks per branch, normalize, o1 - lam*o2 ----------
__global__ __launch_bounds__(256) void diff_combine(
    const float* __restrict__ part,
    const float* __restrict__ lq1, const float* __restrict__ lq2,
    const float* __restrict__ lk1, const float* __restrict__ lk2,
    float* __restrict__ out, int ncs) {
    const int t = blockIdx.x, b = blockIdx.y;
    const int tid = threadIdx.x;
    const int nc = 1 << ncs;
    const int n = (t | 1) + 1;
    __shared__ float sl[2][64];
    __shared__ float s_lam;

    const float* recbase = part + (((size_t)(b * 64 + t) << ncs)) * 2 * REC_FLOATS;

    if (tid < 64) {
        float s1 = lq1[tid] * lk1[tid];
        float s2 = lq2[tid] * lk2[tid];
        for (int off = 32; off > 0; off >>= 1) {
            s1 += __shfl_xor(s1, off);
            s2 += __shfl_xor(s2, off);
        }
        if (tid == 0) s_lam = expf(s1) - expf(s2) + LAMBDA_INIT;
    }
    if (tid < 128) {
        int r = tid & 63, br = tid >> 6;
        float acc = 0.f;
        for (int c = 0; c < nc; ++c) {
            int lo = (c * n) >> ncs, hi = ((c + 1) * n) >> ncs;
            if (lo >= hi || lo > t) continue;
            acc += recbase[(c * 2 + br) * REC_FLOATS + r];
        }
        sl[br][r] = acc;
    }
    __syncthreads();
    const float lam = s_lam;

    float* op = out + ((size_t)b * 4096 + (size_t)t * 64) * 128;
    for (int grp = 0; grp < 4; ++grp) {
        int gid = grp * 256 + tid;
        int e = gid * 8;
        int row = e >> 7;
        float o1[8] = {0, 0, 0, 0, 0, 0, 0, 0}, o2[8] = {0, 0, 0, 0, 0, 0, 0, 0};
        for (int c = 0; c < nc; ++c) {
            int lo = (c * n) >> ncs, hi = ((c + 1) * n) >> ncs;
            if (lo >= hi || lo > t) continue;
            const unsigned short* O0 = (const unsigned short*)(recbase + (c * 2 + 0) * REC_FLOATS + 64);
            const unsigned short* O1 = (const unsigned short*)(recbase + (c * 2 + 1) * REC_FLOATS + 64);
            uint4 u0 = *(const uint4*)&O0[e];
            uint4 u1 = *(const uint4*)&O1[e];
            const unsigned short* e0 = (const unsigned short*)&u0;
            const unsigned short* e1 = (const unsigned short*)&u1;
            #pragma unroll
            for (int j = 0; j < 8; ++j) {
                o1[j] += bf2f(e0[j]);
                o2[j] += bf2f(e1[j]);
            }
        }
        float l1inv = 1.0f / sl[0][row], l2inv = 1.0f / sl[1][row];
        float res[8];
        #pragma unroll
        for (int j = 0; j < 8; ++j) res[j] = o1[j] * l1inv - lam * o2[j] * l2inv;
        *(float4*)&op[e] = *(float4*)&res[0];
        *(float4*)&op[e + 4] = *(float4*)&res[4];
    }
}

extern "C" void kernel_launch(void* const* d_in, const int* in_sizes, int n_in,
                              void* d_out, int out_size, void* d_ws, size_t ws_size,
                              hipStream_t stream) {
    const float* x   = (const float*)d_in[0];
    const float* Wq  = (const float*)d_in[1];
    const float* Wk  = (const float*)d_in[2];
    const float* Wv  = (const float*)d_in[3];
    const float* lq1 = (const float*)d_in[4];
    const float* lq2 = (const float*)d_in[5];
    const float* lk1 = (const float*)d_in[6];
    const float* lk2 = (const float*)d_in[7];
    float* out = (float*)d_out;
    unsigned short* qkv = (unsigned short*)d_ws;

    const int ncs = 2;  // 4 kv-chunks
    const size_t part_bytes = (size_t)256 * (1 << ncs) * 2 * REC_FLOATS * 4;
    float* part = (float*)((char*)d_ws + PART_OFF_BYTES);
    unsigned short* WT = (unsigned short*)((char*)d_ws + PART_OFF_BYTES + part_bytes);

    prep_wt<<<dim3(16, 2, 3), 256, 0, stream>>>(Wq, Wk, Wv, WT);
    qkv_fused<<<dim3(256, 2), 512, 0, stream>>>(x, WT, qkv);

    const unsigned short* qb = qkv;
    const unsigned short* kb = qkv + K_OFF;
    const unsigned short* vtb = qkv + VT_OFF;
    diff_attn_pair<<<dim3(32, 4, 2 << ncs), 256, 0, stream>>>(qb, kb, vtb, part, ncs);
    diff_combine<<<dim3(64, 4), 256, 0, stream>>>(part, lq1, lq2, lk1, lk2, out, ncs);
}